// Round 9
// baseline (252.910 us; speedup 1.0000x reference)
//
#include <hip/hip_runtime.h>
#include <math.h>

// Problem constants
#define NB   64
#define TT   2048
// Tail-window truncation: output = x[:, 2047]; the only temporal coupling is
// the LIF membrane (decay 0.5/step + hard reset). v(T0)=0 direct error at
// 2047 is 0.5^63; validated in prior rounds (TW=192 matched full scan).
#define TW   64
#define T0   (TT - TW)     // 1984
#define NR   (NB * TW)     // 4096 active rows

typedef float v2f __attribute__((ext_vector_type(2)));

__device__ __forceinline__ float gelu_exact(float x) {
    return 0.5f * x * (1.0f + erff(x * 0.7071067811865476f));
}

// LDS float offsets (81.5 KB)
#define XT_O   0        // [32][128] X tile — resident for all layers (16 KB)
#define WB0_O  4096     // [32x256 | 64x128] W chunk buffer 0 (32 KB)
#define WB1_O  12288    // chunk buffer 1; proj G[32][64] aliases here
#define V1_O   20480    // LIF1 v-state intra-block handoff (256 f)
#define V2_O   20736    // LIF2 v-state intra-block handoff (128 f)
#define LB_TOT 20864

// 128 blocks = 64 batches x 2 window-halves (bid = half*64 + b). Block
// (b,half) owns rows t = half*32 + [0,32); 512 threads = 8 waves x 4 rows.
// X lives in LDS (wave-private rows). W1 AND W2 both ride one double-buffered
// LDS staging pipeline (global->reg one phase early, reg->LDS at the barrier;
// layer l+1's first W1 chunks load during fc2's tail). fc2 is DENSE from LDS:
// spike bits come straight from the wave-uniform ballot masks (scalar
// shift+and feeding the FMA) — no spike tile, no sparse global-latency loop
// (round 8's dominant stall). Cross-block LIF membrane handoff at t=32 via
// per-layer global v-buffers + agent-scope release/acquire (round-8 proven).
// All accumulation orders unchanged (k ascending everywhere, a0+a1+a2+a3 +
// xor-tree LN) -> bit-identical output.
__global__ void __launch_bounds__(512) fused_kernel(
    const float* __restrict__ hist,
    const float* __restrict__ pw1, const float* __restrict__ pb1,
    const float* __restrict__ pw2, const float* __restrict__ pb2,
    const float* __restrict__ fc1w, const float* __restrict__ fc1b,
    const float* __restrict__ n1g,  const float* __restrict__ n1b,
    const float* __restrict__ fc2w, const float* __restrict__ fc2b,
    const float* __restrict__ n2g,  const float* __restrict__ n2b,
    float* __restrict__ v1buf, float* __restrict__ v2buf,
    int* __restrict__ flg1, int* __restrict__ flg2,
    float* __restrict__ out)
{
    __shared__ __align__(16) float LB[LB_TOT];
    __shared__ int FLG[2];
    const int tid = threadIdx.x, wave = tid >> 6, lane = tid & 63;
    const int b = blockIdx.x & 63, half = blockIdx.x >> 6;
    const int row0 = wave * 4;           // block-local rows owned by this wave

    if (tid == 0) { FLG[0] = 0; FLG[1] = 0; }

    float4 ra, rb, rc, rd;   // staging regs: 64B/thread = one 32KB chunk
#define LOADQ(src) { const float4* p_ = (const float4*)(src); \
                     ra = p_[tid]; rb = p_[tid+512]; rc = p_[tid+1024]; rd = p_[tid+1536]; }
#define WRITEQ(off) { float4* q_ = (float4*)&LB[off]; \
                      q_[tid] = ra; q_[tid+512] = rb; q_[tid+1024] = rc; q_[tid+1536] = rd; }
// fc1 chunk: [32 k-rows][256 cols]; lane covers cols 4L..4L+3
#define CONSUME(WOFF, KQ) \
    { \
        _Pragma("unroll 2") \
        for (int k4 = 0; k4 < 8; ++k4) { \
            float4 xr[4]; \
            _Pragma("unroll") \
            for (int r = 0; r < 4; ++r) \
                xr[r] = *(const float4*)&LB[XT_O + (row0+r)*128 + (KQ) + k4*4]; \
            _Pragma("unroll") \
            for (int kk = 0; kk < 4; ++kk) { \
                float4 wv = ((const float4*)&LB[(WOFF) + (k4*4+kk)*256])[lane]; \
                v2f wA, wB; wA.x = wv.x; wA.y = wv.y; wB.x = wv.z; wB.y = wv.w; \
                _Pragma("unroll") \
                for (int r = 0; r < 4; ++r) { \
                    float xv = ((const float*)&xr[r])[kk]; \
                    accA[r] += wA * xv; \
                    accB[r] += wB * xv; \
                } \
            } \
        } \
    }
// fc2 chunk: [64 k-rows][128 cols]; lane covers cols 2L..2L+1. k = 4*j + c
// has spike bit j of mask Mc (ballot bit `lane` = col 4*lane+c). JB = KQ/4.
#define CONSUME2(WOFF, JB) \
    { \
        _Pragma("unroll 2") \
        for (int k4 = 0; k4 < 16; ++k4) { \
            const unsigned sh = (JB) + k4; \
            _Pragma("unroll") \
            for (int kk = 0; kk < 4; ++kk) { \
                float2 wv = ((const float2*)&LB[(WOFF) + (k4*4+kk)*128])[lane]; \
                v2f wp; wp.x = wv.x; wp.y = wv.y; \
                _Pragma("unroll") \
                for (int i = 0; i < 4; ++i) { \
                    float xv = (float)((Mk[kk][i] >> sh) & 1ull); \
                    acc2[i] += wp * xv; \
                } \
            } \
        } \
    }

    LOADQ(fc1w);                               // W1 s0(L0) in flight

    // ---------------- proj1: G = gelu(hist @ pw1 + pb1), wave-local rows ----
    {
        const float* hb = hist + ((size_t)b * TT + T0 + half*32) * 4;
        float w0 = pw1[lane], w1 = pw1[64+lane], w2 = pw1[128+lane], w3 = pw1[192+lane];
        float bb = pb1[lane];
        #pragma unroll
        for (int r = 0; r < 4; ++r) {
            int t = row0 + r;
            float4 h = *(const float4*)(hb + t*4);          // wave-uniform
            LB[WB1_O + t*64 + lane] = gelu_exact(bb + h.x*w0 + h.y*w1 + h.z*w2 + h.w*w3);
        }
    }
    WRITEQ(WB0_O);                             // s0 -> B0 (waits its loads)
    LOADQ(fc1w + 8192);                        // s1(L0) in flight
    // ---------------- proj2: X0 = G @ pw2 + pb2 -> XT (wave-local rows) -----
    {
        float2 bv = ((const float2*)pb2)[lane];
        v2f acc[4];
        #pragma unroll
        for (int r = 0; r < 4; ++r) { acc[r].x = 0.f; acc[r].y = 0.f; }
        #pragma unroll 2
        for (int k4 = 0; k4 < 16; ++k4) {
            float4 xr[4];
            #pragma unroll
            for (int r = 0; r < 4; ++r)
                xr[r] = *(const float4*)&LB[WB1_O + (row0+r)*64 + k4*4];  // own rows
            #pragma unroll
            for (int kk = 0; kk < 4; ++kk) {
                v2f w = ((const v2f*)(pw2 + (k4*4+kk)*128))[lane];
                #pragma unroll
                for (int r = 0; r < 4; ++r) {
                    float xv = ((const float*)&xr[r])[kk];
                    acc[r] += w * xv;
                }
            }
        }
        #pragma unroll
        for (int r = 0; r < 4; ++r) {
            float2 o; o.x = acc[r].x + bv.x; o.y = acc[r].y + bv.y;
            *(float2*)&LB[XT_O + (row0+r)*128 + lane*2] = o;
        }
    }

    #pragma unroll 1
    for (int l = 0; l < 4; ++l) {
        const float* W1l = fc1w + (size_t)l * 32768;
        const float* W1n = fc1w + (size_t)(l < 3 ? l+1 : l) * 32768;
        const float* W2g = fc2w + (size_t)l * 32768;

        // ---- fc1: H = X @ W1; entry: WB0 = W1s0(l), regs = W1s1(l) --------
        v2f accA[4], accB[4];
        #pragma unroll
        for (int r = 0; r < 4; ++r) {
            accA[r].x = 0.f; accA[r].y = 0.f;
            accB[r].x = 0.f; accB[r].y = 0.f;
        }
        __syncthreads(); WRITEQ(WB1_O); LOADQ(W1l + 16384); CONSUME(WB0_O, 0);
        __syncthreads(); WRITEQ(WB0_O); LOADQ(W1l + 24576); CONSUME(WB1_O, 32);
        __syncthreads(); WRITEQ(WB1_O); LOADQ(W2g);         CONSUME(WB0_O, 64);
        __syncthreads(); WRITEQ(WB0_O); LOADQ(W2g + 8192);  CONSUME(WB1_O, 96);
        // now: WB0 = W2c0, regs = W2c1 in flight

        // ---- LN1 (same tree/order) ----
        {
            float4 b1v = ((const float4*)(fc1b + l*256))[lane];
            float4 g1v = ((const float4*)(n1g  + l*256))[lane];
            float4 t1v = ((const float4*)(n1b  + l*256))[lane];
            #pragma unroll
            for (int r = 0; r < 4; ++r) {
                float a0 = accA[r].x + b1v.x, a1 = accA[r].y + b1v.y;
                float a2 = accB[r].x + b1v.z, a3 = accB[r].y + b1v.w;
                float s = a0 + a1 + a2 + a3;
                #pragma unroll
                for (int m = 1; m < 64; m <<= 1) s += __shfl_xor(s, m, 64);
                float mean = s * (1.0f/256.0f);
                float dx = a0-mean, dy = a1-mean, dz = a2-mean, dw = a3-mean;
                float q2 = dx*dx + dy*dy + dz*dz + dw*dw;
                #pragma unroll
                for (int m = 1; m < 64; m <<= 1) q2 += __shfl_xor(q2, m, 64);
                float inv = 1.0f / sqrtf(q2 * (1.0f/256.0f) + 1e-5f);
                accA[r].x = dx*inv*g1v.x + t1v.x; accA[r].y = dy*inv*g1v.y + t1v.y;
                accB[r].x = dz*inv*g1v.z + t1v.z; accB[r].y = dw*inv*g1v.w + t1v.w;
            }
        }
        // ---- LIF1: intra-block flag chain; cross-block seed/emit -----------
        // Masks stay in wave-uniform registers: Mk[c][i] bit j = spike of
        // col d=4j+c at local step i (ballot bit `lane` covers col 4*lane+c).
        unsigned long long Mk[4][4];
        {
            const int tgt = l*8 + wave;
            while (__hip_atomic_load(&FLG[0], __ATOMIC_ACQUIRE,
                                     __HIP_MEMORY_SCOPE_WORKGROUP) < tgt)
                __builtin_amdgcn_s_sleep(1);
            float v0, v1, v2, v3;
            if (wave == 0) {
                if (half == 0) { v0 = v1 = v2 = v3 = 0.f; }
                else {
                    while (__hip_atomic_load(&flg1[b], __ATOMIC_RELAXED,
                                             __HIP_MEMORY_SCOPE_AGENT) < l+1)
                        __builtin_amdgcn_s_sleep(1);
                    __builtin_amdgcn_fence(__ATOMIC_ACQUIRE, "agent");
                    float4 vv = *(const float4*)&v1buf[(size_t)l*NB*256 + b*256 + lane*4];
                    v0 = vv.x; v1 = vv.y; v2 = vv.z; v3 = vv.w;
                }
            } else {
                float4 vv = *(const float4*)&LB[V1_O + lane*4];
                v0 = vv.x; v1 = vv.y; v2 = vv.z; v3 = vv.w;
            }
            #pragma unroll
            for (int i = 0; i < 4; ++i) {
                v0 += (accA[i].x - v0) * 0.5f;
                v1 += (accA[i].y - v1) * 0.5f;
                v2 += (accB[i].x - v2) * 0.5f;
                v3 += (accB[i].y - v3) * 0.5f;
                bool s0 = v0 >= 1.f, s1 = v1 >= 1.f, s2 = v2 >= 1.f, s3 = v3 >= 1.f;
                Mk[0][i] = __ballot(s0); Mk[1][i] = __ballot(s1);
                Mk[2][i] = __ballot(s2); Mk[3][i] = __ballot(s3);
                v0 = s0 ? 0.f : v0;  v1 = s1 ? 0.f : v1;
                v2 = s2 ? 0.f : v2;  v3 = s3 ? 0.f : v3;
            }
            if (wave < 7) {
                float4 vv; vv.x = v0; vv.y = v1; vv.z = v2; vv.w = v3;
                *(float4*)&LB[V1_O + lane*4] = vv;
            } else if (half == 0) {
                float4 vv; vv.x = v0; vv.y = v1; vv.z = v2; vv.w = v3;
                *(float4*)&v1buf[(size_t)l*NB*256 + b*256 + lane*4] = vv;
                __builtin_amdgcn_fence(__ATOMIC_RELEASE, "agent");
                if (lane == 0)
                    __hip_atomic_store(&flg1[b], l+1, __ATOMIC_RELAXED,
                                       __HIP_MEMORY_SCOPE_AGENT);
            }
            if (lane == 0)
                __hip_atomic_store(&FLG[0], tgt+1, __ATOMIC_RELEASE,
                                   __HIP_MEMORY_SCOPE_WORKGROUP);
        }
        // ---- fc2 DENSE from LDS: same staging pipeline, k ascending --------
        v2f acc2[4];
        #pragma unroll
        for (int i = 0; i < 4; ++i) { acc2[i].x = 0.f; acc2[i].y = 0.f; }
        __syncthreads(); WRITEQ(WB1_O); LOADQ(W2g + 16384); CONSUME2(WB0_O, 0);
        __syncthreads(); WRITEQ(WB0_O); LOADQ(W2g + 24576); CONSUME2(WB1_O, 16);
        __syncthreads(); WRITEQ(WB1_O); LOADQ(W1n);         CONSUME2(WB0_O, 32);
        __syncthreads(); WRITEQ(WB0_O); LOADQ(W1n + 8192);  CONSUME2(WB1_O, 48);
        // exit invariant restored: WB0 = W1s0(l+1), regs = W1s1(l+1)

        // ---- LN2 (same tree/order) ----
        {
            float2 b2v = ((const float2*)(fc2b + l*128))[lane];
            float2 g2v = ((const float2*)(n2g  + l*128))[lane];
            float2 t2v = ((const float2*)(n2b  + l*128))[lane];
            #pragma unroll
            for (int i = 0; i < 4; ++i) {
                float ax = acc2[i].x + b2v.x, ay = acc2[i].y + b2v.y;
                float s = ax + ay;
                #pragma unroll
                for (int m = 1; m < 64; m <<= 1) s += __shfl_xor(s, m, 64);
                float mean = s * (1.0f/128.0f);
                float dx = ax - mean, dy = ay - mean;
                float q = dx*dx + dy*dy;
                #pragma unroll
                for (int m = 1; m < 64; m <<= 1) q += __shfl_xor(q, m, 64);
                float inv = 1.0f / sqrtf(q * (1.0f/128.0f) + 1e-5f);
                acc2[i].x = dx*inv*g2v.x + t2v.x;
                acc2[i].y = dy*inv*g2v.y + t2v.y;
            }
        }
        // ---- LIF2 + residual on LDS X tile; cross-block seed/emit ----------
        {
            const int tgt = l*8 + wave;
            while (__hip_atomic_load(&FLG[1], __ATOMIC_ACQUIRE,
                                     __HIP_MEMORY_SCOPE_WORKGROUP) < tgt)
                __builtin_amdgcn_s_sleep(1);
            float u0, u1;
            if (wave == 0) {
                if (half == 0) { u0 = u1 = 0.f; }
                else {
                    while (__hip_atomic_load(&flg2[b], __ATOMIC_RELAXED,
                                             __HIP_MEMORY_SCOPE_AGENT) < l+1)
                        __builtin_amdgcn_s_sleep(1);
                    __builtin_amdgcn_fence(__ATOMIC_ACQUIRE, "agent");
                    float2 uv = *(const float2*)&v2buf[(size_t)l*NB*128 + b*128 + lane*2];
                    u0 = uv.x; u1 = uv.y;
                }
            } else {
                float2 uv = *(const float2*)&LB[V2_O + lane*2];
                u0 = uv.x; u1 = uv.y;
            }
            #pragma unroll
            for (int i = 0; i < 4; ++i) {
                int t = row0 + i;
                u0 += (acc2[i].x - u0) * 0.5f;
                u1 += (acc2[i].y - u1) * 0.5f;
                bool s0 = u0 >= 1.f, s1 = u1 >= 1.f;
                float2 xv = *(const float2*)&LB[XT_O + t*128 + lane*2];
                float2 xn;
                xn.x = xv.x + (s0 ? 1.f : 0.f);
                xn.y = xv.y + (s1 ? 1.f : 0.f);
                *(float2*)&LB[XT_O + t*128 + lane*2] = xn;
                u0 = s0 ? 0.f : u0;
                u1 = s1 ? 0.f : u1;
                if (l == 3 && half == 1 && t == 31)
                    ((float2*)(out + b*128))[lane] = xn;     // row t=2047
            }
            if (wave < 7) {
                float2 uv; uv.x = u0; uv.y = u1;
                *(float2*)&LB[V2_O + lane*2] = uv;
            } else if (half == 0) {
                float2 uv; uv.x = u0; uv.y = u1;
                *(float2*)&v2buf[(size_t)l*NB*128 + b*128 + lane*2] = uv;
                __builtin_amdgcn_fence(__ATOMIC_RELEASE, "agent");
                if (lane == 0)
                    __hip_atomic_store(&flg2[b], l+1, __ATOMIC_RELAXED,
                                       __HIP_MEMORY_SCOPE_AGENT);
            }
            if (lane == 0)
                __hip_atomic_store(&FLG[1], tgt+1, __ATOMIC_RELEASE,
                                   __HIP_MEMORY_SCOPE_WORKGROUP);
        }
    }
#undef LOADQ
#undef WRITEQ
#undef CONSUME
#undef CONSUME2
}

extern "C" void kernel_launch(void* const* d_in, const int* in_sizes, int n_in,
                              void* d_out, int out_size, void* d_ws, size_t ws_size,
                              hipStream_t stream) {
    const float* hist = (const float*)d_in[0];
    const float* pw1  = (const float*)d_in[1];
    const float* pb1  = (const float*)d_in[2];
    const float* pw2  = (const float*)d_in[3];
    const float* pb2  = (const float*)d_in[4];
    const float* fc1w = (const float*)d_in[5];
    const float* fc1b = (const float*)d_in[6];
    const float* n1g  = (const float*)d_in[7];
    const float* n1b  = (const float*)d_in[8];
    const float* fc2w = (const float*)d_in[9];
    const float* fc2b = (const float*)d_in[10];
    const float* n2g  = (const float*)d_in[11];
    const float* n2b  = (const float*)d_in[12];
    float* out = (float*)d_out;

    char* ws = (char*)d_ws;
    float* v1buf = (float*)ws;                      // [4][64][256] = 256 KB
    float* v2buf = (float*)(ws + (1ull << 20));     // [4][64][128] = 128 KB
    int*   flg1  = (int*)(ws + (2ull << 20));       // [64]
    int*   flg2  = flg1 + 64;

    hipMemsetAsync(flg1, 0, 128 * sizeof(int), stream);
    fused_kernel<<<128, 512, 0, stream>>>(hist, pw1, pb1, pw2, pb2,
                                          fc1w, fc1b, n1g, n1b,
                                          fc2w, fc2b, n2g, n2b,
                                          v1buf, v2buf, flg1, flg2, out);
}

// Round 10
// 182.548 us; speedup vs baseline: 1.3854x; 1.3854x over previous
//
#include <hip/hip_runtime.h>
#include <math.h>

// Problem constants
#define NB   64
#define TT   2048
// Tail-window truncation: output = x[:, 2047]; the only temporal coupling is
// the LIF membrane (decay 0.5/step + hard reset). v(T0)=0 direct error at
// 2047 is 0.5^63; validated in prior rounds (TW=192 matched full scan).
#define TW   64
#define T0   (TT - TW)     // 1984
#define NR   (NB * TW)     // 4096 active rows

typedef float v2f __attribute__((ext_vector_type(2)));

__device__ __forceinline__ float gelu_exact(float x) {
    return 0.5f * x * (1.0f + erff(x * 0.7071067811865476f));
}

// LDS float offsets (145.5 KB + pad; 1 block/CU regime)
#define XT_O   0        // [32][128] X tile — resident for all layers (16 KB)
#define WB0_O  4096     // [64][256] W1 half buffer 0 (64 KB)
#define WB1_O  20480    // half buffer 1; proj G[32][64] aliases here
#define V1_O   36864    // LIF1 v-state intra-block handoff (256 f)
#define V2_O   37120    // LIF2 v-state intra-block handoff (128 f)
#define LB_TOT 37248

// 128 blocks = 64 batches x 2 window-halves (bid = half*64 + b). Block
// (b,half) owns rows t = half*32 + [0,32); 512 threads = 8 waves x 4 rows.
// Round-8 structure (verified 127.5us) + three fixes:
//  (1) W1 staged as 2x64KB halves (8 barriers total, 8-deep load batches)
//  (2) fc2 sparse loop ILP-4: pop 4 ascending spike indices (scalar ctz
//      chain, no arrays), issue 16 loads, accumulate in the identical
//      ascending order -> 4x fewer exposed L2 latencies
//  (3) ballot masks stay in wave-uniform registers (no MSK LDS round-trip)
// X lives in LDS (wave-private rows). Cross-block LIF membrane handoff at
// t=32 via per-layer global v-buffers + agent-scope release/acquire.
// All accumulation orders unchanged (k ascending, a0+a1+a2+a3 + xor-tree LN,
// d-ascending sparse fc2 with exact-zero adds) -> bit-identical output.
__global__ void __launch_bounds__(512) fused_kernel(
    const float* __restrict__ hist,
    const float* __restrict__ pw1, const float* __restrict__ pb1,
    const float* __restrict__ pw2, const float* __restrict__ pb2,
    const float* __restrict__ fc1w, const float* __restrict__ fc1b,
    const float* __restrict__ n1g,  const float* __restrict__ n1b,
    const float* __restrict__ fc2w, const float* __restrict__ fc2b,
    const float* __restrict__ n2g,  const float* __restrict__ n2b,
    float* __restrict__ v1buf, float* __restrict__ v2buf,
    int* __restrict__ flg1, int* __restrict__ flg2,
    float* __restrict__ out)
{
    __shared__ __align__(16) float LB[LB_TOT];
    __shared__ int FLG[2];
    const int tid = threadIdx.x, wave = tid >> 6, lane = tid & 63;
    const int b = blockIdx.x & 63, half = blockIdx.x >> 6;
    const int row0 = wave * 4;           // block-local rows owned by this wave

    if (tid == 0) { FLG[0] = 0; FLG[1] = 0; }

    float4 r0, r1, r2, r3, r4, r5, r6, r7;   // staging: 128B/thread = 64KB half
#define LOADQ(src) { const float4* p_ = (const float4*)(src); \
                     r0 = p_[tid];        r1 = p_[tid + 512]; \
                     r2 = p_[tid + 1024]; r3 = p_[tid + 1536]; \
                     r4 = p_[tid + 2048]; r5 = p_[tid + 2560]; \
                     r6 = p_[tid + 3072]; r7 = p_[tid + 3584]; }
#define WRITEQ(off) { float4* q_ = (float4*)&LB[off]; \
                      q_[tid]        = r0; q_[tid + 512]  = r1; \
                      q_[tid + 1024] = r2; q_[tid + 1536] = r3; \
                      q_[tid + 2048] = r4; q_[tid + 2560] = r5; \
                      q_[tid + 3072] = r6; q_[tid + 3584] = r7; }
// W1 half: [64 k-rows][256 cols]; lane covers cols 4L..4L+3
#define CONSUME(WOFF, KQ) \
    { \
        _Pragma("unroll 2") \
        for (int k4 = 0; k4 < 16; ++k4) { \
            float4 xr[4]; \
            _Pragma("unroll") \
            for (int r = 0; r < 4; ++r) \
                xr[r] = *(const float4*)&LB[XT_O + (row0+r)*128 + (KQ) + k4*4]; \
            _Pragma("unroll") \
            for (int kk = 0; kk < 4; ++kk) { \
                float4 wv = ((const float4*)&LB[(WOFF) + (k4*4+kk)*256])[lane]; \
                v2f wA, wB; wA.x = wv.x; wA.y = wv.y; wB.x = wv.z; wB.y = wv.w; \
                _Pragma("unroll") \
                for (int r = 0; r < 4; ++r) { \
                    float xv = ((const float*)&xr[r])[kk]; \
                    accA[r] += wA * xv; \
                    accB[r] += wB * xv; \
                } \
            } \
        } \
    }

    LOADQ(fc1w);                               // W1 h0(L0) in flight

    // ---------------- proj1: G = gelu(hist @ pw1 + pb1), wave-local rows ----
    {
        const float* hb = hist + ((size_t)b * TT + T0 + half*32) * 4;
        float w0 = pw1[lane], w1 = pw1[64+lane], w2 = pw1[128+lane], w3 = pw1[192+lane];
        float bb = pb1[lane];
        #pragma unroll
        for (int r = 0; r < 4; ++r) {
            int t = row0 + r;
            float4 h = *(const float4*)(hb + t*4);          // wave-uniform
            LB[WB1_O + t*64 + lane] = gelu_exact(bb + h.x*w0 + h.y*w1 + h.z*w2 + h.w*w3);
        }
    }
    WRITEQ(WB0_O);                             // h0 -> B0 (waits its loads)
    LOADQ(fc1w + 16384);                       // h1(L0) in flight
    // ---------------- proj2: X0 = G @ pw2 + pb2 -> XT (wave-local rows) -----
    {
        float2 bv = ((const float2*)pb2)[lane];
        v2f acc[4];
        #pragma unroll
        for (int r = 0; r < 4; ++r) { acc[r].x = 0.f; acc[r].y = 0.f; }
        #pragma unroll 2
        for (int k4 = 0; k4 < 16; ++k4) {
            float4 xr[4];
            #pragma unroll
            for (int r = 0; r < 4; ++r)
                xr[r] = *(const float4*)&LB[WB1_O + (row0+r)*64 + k4*4];  // own rows
            #pragma unroll
            for (int kk = 0; kk < 4; ++kk) {
                v2f w = ((const v2f*)(pw2 + (k4*4+kk)*128))[lane];
                #pragma unroll
                for (int r = 0; r < 4; ++r) {
                    float xv = ((const float*)&xr[r])[kk];
                    acc[r] += w * xv;
                }
            }
        }
        #pragma unroll
        for (int r = 0; r < 4; ++r) {
            float2 o; o.x = acc[r].x + bv.x; o.y = acc[r].y + bv.y;
            *(float2*)&LB[XT_O + (row0+r)*128 + lane*2] = o;
        }
    }

    #pragma unroll 1
    for (int l = 0; l < 4; ++l) {
        const float* W1n = fc1w + (size_t)(l < 3 ? l+1 : l) * 32768;
        const float* W2g = fc2w + (size_t)l * 32768;

        // ---- fc1: H = X @ W1; entry: WB0 = h0(l), regs = h1(l) in flight ---
        v2f accA[4], accB[4];
        #pragma unroll
        for (int r = 0; r < 4; ++r) {
            accA[r].x = 0.f; accA[r].y = 0.f;
            accB[r].x = 0.f; accB[r].y = 0.f;
        }
        __syncthreads(); WRITEQ(WB1_O); LOADQ(W1n);          CONSUME(WB0_O, 0);
        __syncthreads(); WRITEQ(WB0_O); LOADQ(W1n + 16384);  CONSUME(WB1_O, 64);
        // exit: WB0 = h0(l+1) written, regs = h1(l+1) in flight

        // ---- LN1 (same tree/order) ----
        {
            float4 b1v = ((const float4*)(fc1b + l*256))[lane];
            float4 g1v = ((const float4*)(n1g  + l*256))[lane];
            float4 t1v = ((const float4*)(n1b  + l*256))[lane];
            #pragma unroll
            for (int r = 0; r < 4; ++r) {
                float a0 = accA[r].x + b1v.x, a1 = accA[r].y + b1v.y;
                float a2 = accB[r].x + b1v.z, a3 = accB[r].y + b1v.w;
                float s = a0 + a1 + a2 + a3;
                #pragma unroll
                for (int m = 1; m < 64; m <<= 1) s += __shfl_xor(s, m, 64);
                float mean = s * (1.0f/256.0f);
                float dx = a0-mean, dy = a1-mean, dz = a2-mean, dw = a3-mean;
                float q2 = dx*dx + dy*dy + dz*dz + dw*dw;
                #pragma unroll
                for (int m = 1; m < 64; m <<= 1) q2 += __shfl_xor(q2, m, 64);
                float inv = 1.0f / sqrtf(q2 * (1.0f/256.0f) + 1e-5f);
                accA[r].x = dx*inv*g1v.x + t1v.x; accA[r].y = dy*inv*g1v.y + t1v.y;
                accB[r].x = dz*inv*g1v.z + t1v.z; accB[r].y = dw*inv*g1v.w + t1v.w;
            }
        }
        // ---- LIF1: intra-block flag chain; cross-block seed/emit -----------
        // Mk[c][i] bit j = spike of col d=4j+c at local step i (reg-resident).
        unsigned long long Mk[4][4];
        {
            const int tgt = l*8 + wave;
            while (__hip_atomic_load(&FLG[0], __ATOMIC_ACQUIRE,
                                     __HIP_MEMORY_SCOPE_WORKGROUP) < tgt)
                __builtin_amdgcn_s_sleep(1);
            float v0, v1, v2, v3;
            if (wave == 0) {
                if (half == 0) { v0 = v1 = v2 = v3 = 0.f; }
                else {
                    while (__hip_atomic_load(&flg1[b], __ATOMIC_RELAXED,
                                             __HIP_MEMORY_SCOPE_AGENT) < l+1)
                        __builtin_amdgcn_s_sleep(1);
                    __builtin_amdgcn_fence(__ATOMIC_ACQUIRE, "agent");
                    float4 vv = *(const float4*)&v1buf[(size_t)l*NB*256 + b*256 + lane*4];
                    v0 = vv.x; v1 = vv.y; v2 = vv.z; v3 = vv.w;
                }
            } else {
                float4 vv = *(const float4*)&LB[V1_O + lane*4];
                v0 = vv.x; v1 = vv.y; v2 = vv.z; v3 = vv.w;
            }
            #pragma unroll
            for (int i = 0; i < 4; ++i) {
                v0 += (accA[i].x - v0) * 0.5f;
                v1 += (accA[i].y - v1) * 0.5f;
                v2 += (accB[i].x - v2) * 0.5f;
                v3 += (accB[i].y - v3) * 0.5f;
                bool s0 = v0 >= 1.f, s1 = v1 >= 1.f, s2 = v2 >= 1.f, s3 = v3 >= 1.f;
                Mk[0][i] = __ballot(s0); Mk[1][i] = __ballot(s1);
                Mk[2][i] = __ballot(s2); Mk[3][i] = __ballot(s3);
                v0 = s0 ? 0.f : v0;  v1 = s1 ? 0.f : v1;
                v2 = s2 ? 0.f : v2;  v3 = s3 ? 0.f : v3;
            }
            if (wave < 7) {
                float4 vv; vv.x = v0; vv.y = v1; vv.z = v2; vv.w = v3;
                *(float4*)&LB[V1_O + lane*4] = vv;
            } else if (half == 0) {
                float4 vv; vv.x = v0; vv.y = v1; vv.z = v2; vv.w = v3;
                *(float4*)&v1buf[(size_t)l*NB*256 + b*256 + lane*4] = vv;
                __builtin_amdgcn_fence(__ATOMIC_RELEASE, "agent");
                if (lane == 0)
                    __hip_atomic_store(&flg1[b], l+1, __ATOMIC_RELAXED,
                                       __HIP_MEMORY_SCOPE_AGENT);
            }
            if (lane == 0)
                __hip_atomic_store(&FLG[0], tgt+1, __ATOMIC_RELEASE,
                                   __HIP_MEMORY_SCOPE_WORKGROUP);
        }
        // ---- fc2 sparse, ILP-4: 4 ascending indices per iter, 16 loads
        //      issued together, adds in identical ascending order ------------
        float a2x[4], a2y[4];
        #pragma unroll
        for (int i = 0; i < 4; ++i) {
            unsigned long long m0 = Mk[0][i], m1 = Mk[1][i];
            unsigned long long m2 = Mk[2][i], m3 = Mk[3][i];
            unsigned long long mm = m0 | m1 | m2 | m3;
            float ax = 0.f, ay = 0.f;
            int ng = __popcll(mm) >> 2;
            for (int g = 0; g < ng; ++g) {
                int i0 = __builtin_ctzll(mm); mm &= mm - 1;
                int i1 = __builtin_ctzll(mm); mm &= mm - 1;
                int i2 = __builtin_ctzll(mm); mm &= mm - 1;
                int i3 = __builtin_ctzll(mm); mm &= mm - 1;
                const float* p0 = W2g + (size_t)i0 * 512;
                const float* p1 = W2g + (size_t)i1 * 512;
                const float* p2 = W2g + (size_t)i2 * 512;
                const float* p3 = W2g + (size_t)i3 * 512;
                float2 w00 = ((const float2*)(p0      ))[lane];
                float2 w01 = ((const float2*)(p0 + 128))[lane];
                float2 w02 = ((const float2*)(p0 + 256))[lane];
                float2 w03 = ((const float2*)(p0 + 384))[lane];
                float2 w10 = ((const float2*)(p1      ))[lane];
                float2 w11 = ((const float2*)(p1 + 128))[lane];
                float2 w12 = ((const float2*)(p1 + 256))[lane];
                float2 w13 = ((const float2*)(p1 + 384))[lane];
                float2 w20 = ((const float2*)(p2      ))[lane];
                float2 w21 = ((const float2*)(p2 + 128))[lane];
                float2 w22 = ((const float2*)(p2 + 256))[lane];
                float2 w23 = ((const float2*)(p2 + 384))[lane];
                float2 w30 = ((const float2*)(p3      ))[lane];
                float2 w31 = ((const float2*)(p3 + 128))[lane];
                float2 w32 = ((const float2*)(p3 + 256))[lane];
                float2 w33 = ((const float2*)(p3 + 384))[lane];
                unsigned long long b0 = 1ull << i0, b1 = 1ull << i1;
                unsigned long long b2 = 1ull << i2, b3 = 1ull << i3;
                ax += (m0 & b0) ? w00.x : 0.f;  ay += (m0 & b0) ? w00.y : 0.f;
                ax += (m1 & b0) ? w01.x : 0.f;  ay += (m1 & b0) ? w01.y : 0.f;
                ax += (m2 & b0) ? w02.x : 0.f;  ay += (m2 & b0) ? w02.y : 0.f;
                ax += (m3 & b0) ? w03.x : 0.f;  ay += (m3 & b0) ? w03.y : 0.f;
                ax += (m0 & b1) ? w10.x : 0.f;  ay += (m0 & b1) ? w10.y : 0.f;
                ax += (m1 & b1) ? w11.x : 0.f;  ay += (m1 & b1) ? w11.y : 0.f;
                ax += (m2 & b1) ? w12.x : 0.f;  ay += (m2 & b1) ? w12.y : 0.f;
                ax += (m3 & b1) ? w13.x : 0.f;  ay += (m3 & b1) ? w13.y : 0.f;
                ax += (m0 & b2) ? w20.x : 0.f;  ay += (m0 & b2) ? w20.y : 0.f;
                ax += (m1 & b2) ? w21.x : 0.f;  ay += (m1 & b2) ? w21.y : 0.f;
                ax += (m2 & b2) ? w22.x : 0.f;  ay += (m2 & b2) ? w22.y : 0.f;
                ax += (m3 & b2) ? w23.x : 0.f;  ay += (m3 & b2) ? w23.y : 0.f;
                ax += (m0 & b3) ? w30.x : 0.f;  ay += (m0 & b3) ? w30.y : 0.f;
                ax += (m1 & b3) ? w31.x : 0.f;  ay += (m1 & b3) ? w31.y : 0.f;
                ax += (m2 & b3) ? w32.x : 0.f;  ay += (m2 & b3) ? w32.y : 0.f;
                ax += (m3 & b3) ? w33.x : 0.f;  ay += (m3 & b3) ? w33.y : 0.f;
            }
            while (mm) {                       // tail (<=3), same order
                int id = __builtin_ctzll(mm); mm &= mm - 1;
                const float* wr = W2g + (size_t)id * 512;
                float2 w0 = ((const float2*)(wr      ))[lane];
                float2 w1 = ((const float2*)(wr + 128))[lane];
                float2 w2 = ((const float2*)(wr + 256))[lane];
                float2 w3 = ((const float2*)(wr + 384))[lane];
                unsigned long long bit = 1ull << id;
                ax += (m0 & bit) ? w0.x : 0.f;  ay += (m0 & bit) ? w0.y : 0.f;
                ax += (m1 & bit) ? w1.x : 0.f;  ay += (m1 & bit) ? w1.y : 0.f;
                ax += (m2 & bit) ? w2.x : 0.f;  ay += (m2 & bit) ? w2.y : 0.f;
                ax += (m3 & bit) ? w3.x : 0.f;  ay += (m3 & bit) ? w3.y : 0.f;
            }
            a2x[i] = ax; a2y[i] = ay;
        }
        // ---- LN2 (same tree/order) ----
        {
            float2 b2v = ((const float2*)(fc2b + l*128))[lane];
            float2 g2v = ((const float2*)(n2g  + l*128))[lane];
            float2 t2v = ((const float2*)(n2b  + l*128))[lane];
            #pragma unroll
            for (int i = 0; i < 4; ++i) {
                float ax = a2x[i] + b2v.x, ay = a2y[i] + b2v.y;
                float s = ax + ay;
                #pragma unroll
                for (int m = 1; m < 64; m <<= 1) s += __shfl_xor(s, m, 64);
                float mean = s * (1.0f/128.0f);
                float dx = ax - mean, dy = ay - mean;
                float q = dx*dx + dy*dy;
                #pragma unroll
                for (int m = 1; m < 64; m <<= 1) q += __shfl_xor(q, m, 64);
                float inv = 1.0f / sqrtf(q * (1.0f/128.0f) + 1e-5f);
                a2x[i] = dx*inv*g2v.x + t2v.x;
                a2y[i] = dy*inv*g2v.y + t2v.y;
            }
        }
        // ---- LIF2 + residual on LDS X tile; cross-block seed/emit ----------
        {
            const int tgt = l*8 + wave;
            while (__hip_atomic_load(&FLG[1], __ATOMIC_ACQUIRE,
                                     __HIP_MEMORY_SCOPE_WORKGROUP) < tgt)
                __builtin_amdgcn_s_sleep(1);
            float u0, u1;
            if (wave == 0) {
                if (half == 0) { u0 = u1 = 0.f; }
                else {
                    while (__hip_atomic_load(&flg2[b], __ATOMIC_RELAXED,
                                             __HIP_MEMORY_SCOPE_AGENT) < l+1)
                        __builtin_amdgcn_s_sleep(1);
                    __builtin_amdgcn_fence(__ATOMIC_ACQUIRE, "agent");
                    float2 uv = *(const float2*)&v2buf[(size_t)l*NB*128 + b*128 + lane*2];
                    u0 = uv.x; u1 = uv.y;
                }
            } else {
                float2 uv = *(const float2*)&LB[V2_O + lane*2];
                u0 = uv.x; u1 = uv.y;
            }
            #pragma unroll
            for (int i = 0; i < 4; ++i) {
                int t = row0 + i;
                u0 += (a2x[i] - u0) * 0.5f;
                u1 += (a2y[i] - u1) * 0.5f;
                bool s0 = u0 >= 1.f, s1 = u1 >= 1.f;
                float2 xv = *(const float2*)&LB[XT_O + t*128 + lane*2];
                float2 xn;
                xn.x = xv.x + (s0 ? 1.f : 0.f);
                xn.y = xv.y + (s1 ? 1.f : 0.f);
                *(float2*)&LB[XT_O + t*128 + lane*2] = xn;
                u0 = s0 ? 0.f : u0;
                u1 = s1 ? 0.f : u1;
                if (l == 3 && half == 1 && t == 31)
                    ((float2*)(out + b*128))[lane] = xn;     // row t=2047
            }
            if (wave < 7) {
                float2 uv; uv.x = u0; uv.y = u1;
                *(float2*)&LB[V2_O + lane*2] = uv;
            } else if (half == 0) {
                float2 uv; uv.x = u0; uv.y = u1;
                *(float2*)&v2buf[(size_t)l*NB*128 + b*128 + lane*2] = uv;
                __builtin_amdgcn_fence(__ATOMIC_RELEASE, "agent");
                if (lane == 0)
                    __hip_atomic_store(&flg2[b], l+1, __ATOMIC_RELAXED,
                                       __HIP_MEMORY_SCOPE_AGENT);
            }
            if (lane == 0)
                __hip_atomic_store(&FLG[1], tgt+1, __ATOMIC_RELEASE,
                                   __HIP_MEMORY_SCOPE_WORKGROUP);
        }
    }
#undef LOADQ
#undef WRITEQ
#undef CONSUME
}

extern "C" void kernel_launch(void* const* d_in, const int* in_sizes, int n_in,
                              void* d_out, int out_size, void* d_ws, size_t ws_size,
                              hipStream_t stream) {
    const float* hist = (const float*)d_in[0];
    const float* pw1  = (const float*)d_in[1];
    const float* pb1  = (const float*)d_in[2];
    const float* pw2  = (const float*)d_in[3];
    const float* pb2  = (const float*)d_in[4];
    const float* fc1w = (const float*)d_in[5];
    const float* fc1b = (const float*)d_in[6];
    const float* n1g  = (const float*)d_in[7];
    const float* n1b  = (const float*)d_in[8];
    const float* fc2w = (const float*)d_in[9];
    const float* fc2b = (const float*)d_in[10];
    const float* n2g  = (const float*)d_in[11];
    const float* n2b  = (const float*)d_in[12];
    float* out = (float*)d_out;

    char* ws = (char*)d_ws;
    float* v1buf = (float*)ws;                      // [4][64][256] = 256 KB
    float* v2buf = (float*)(ws + (1ull << 20));     // [4][64][128] = 128 KB
    int*   flg1  = (int*)(ws + (2ull << 20));       // [64]
    int*   flg2  = flg1 + 64;

    hipMemsetAsync(flg1, 0, 128 * sizeof(int), stream);
    fused_kernel<<<128, 512, 0, stream>>>(hist, pw1, pb1, pw2, pb2,
                                          fc1w, fc1b, n1g, n1b,
                                          fc2w, fc2b, n2g, n2b,
                                          v1buf, v2buf, flg1, flg2, out);
}

// Round 11
// 176.816 us; speedup vs baseline: 1.4304x; 1.0324x over previous
//
#include <hip/hip_runtime.h>
#include <math.h>

// Problem constants
#define NB   64
#define TT   2048
// Tail-window truncation: output = x[:, 2047]; the only temporal coupling is
// the LIF membrane (decay 0.5/step + hard reset). v(T0)=0 direct error at
// 2047 is 0.5^63; validated in prior rounds (TW=192 matched full scan).
#define TW   64
#define T0   (TT - TW)     // 1984
#define NR   (NB * TW)     // 4096 active rows

typedef float v2f __attribute__((ext_vector_type(2)));

__device__ __forceinline__ float gelu_exact(float x) {
    return 0.5f * x * (1.0f + erff(x * 0.7071067811865476f));
}

// LDS float offsets (137.5 KB; 1 block/CU)
#define XT_O   0        // [16][128] X tile — resident for all layers (8 KB)
#define WB0_O  2048     // [64][256] W1 half buffer 0 (64 KB)
#define WB1_O  18432    // half buffer 1; proj G[16][64] aliases here
#define V1_O   34816    // LIF1 v-state intra-block handoff (256 f)
#define V2_O   35072    // LIF2 v-state intra-block handoff (128 f)
#define LB_TOT 35200

// 256 blocks = 64 batches x 4 window-quarters (bid = q*64 + b; partners share
// an XCD). Block (b,q) owns rows t = q*16 + [0,16); 512 threads = 8 waves x
// 2 rows. Full-chip occupancy: per-CU VALU and X-broadcast LDS reads halve
// vs round 10 (both scale with rows/block); W-LDS reads unchanged (scale
// with waves). Same verified pieces: W1 staged as 2x64KB double-buffered
// halves (loads one phase ahead, cross-layer prefetch), fc2 sparse ILP-4
// from reg-resident ballot masks, 8-stage intra-block LIF flag chains.
// Cross-quarter LIF membrane ladder: quarter q's last wave writes v to a
// per-(layer,boundary) global buffer + agent release; quarter q+1's first
// wave acquire-spins. Quarters pipeline across layers (systolic skew), so
// ladder cost is ~3 skews total, not per-layer serial. All accumulation
// orders unchanged (k ascending, a0+a1+a2+a3 + xor-tree LN, d-ascending
// sparse fc2 with exact-zero adds) -> bit-identical output.
__global__ void __launch_bounds__(512) fused_kernel(
    const float* __restrict__ hist,
    const float* __restrict__ pw1, const float* __restrict__ pb1,
    const float* __restrict__ pw2, const float* __restrict__ pb2,
    const float* __restrict__ fc1w, const float* __restrict__ fc1b,
    const float* __restrict__ n1g,  const float* __restrict__ n1b,
    const float* __restrict__ fc2w, const float* __restrict__ fc2b,
    const float* __restrict__ n2g,  const float* __restrict__ n2b,
    float* __restrict__ v1buf, float* __restrict__ v2buf,
    int* __restrict__ flg1, int* __restrict__ flg2,
    float* __restrict__ out)
{
    __shared__ __align__(16) float LB[LB_TOT];
    __shared__ int FLG[2];
    const int tid = threadIdx.x, wave = tid >> 6, lane = tid & 63;
    const int b = blockIdx.x & 63, q = blockIdx.x >> 6;
    const int row0 = wave * 2;           // block-local rows owned by this wave

    if (tid == 0) { FLG[0] = 0; FLG[1] = 0; }

    float4 r0, r1, r2, r3, r4, r5, r6, r7;   // staging: 128B/thread = 64KB half
#define LOADQ(src) { const float4* p_ = (const float4*)(src); \
                     r0 = p_[tid];        r1 = p_[tid + 512]; \
                     r2 = p_[tid + 1024]; r3 = p_[tid + 1536]; \
                     r4 = p_[tid + 2048]; r5 = p_[tid + 2560]; \
                     r6 = p_[tid + 3072]; r7 = p_[tid + 3584]; }
#define WRITEQ(off) { float4* q_ = (float4*)&LB[off]; \
                      q_[tid]        = r0; q_[tid + 512]  = r1; \
                      q_[tid + 1024] = r2; q_[tid + 1536] = r3; \
                      q_[tid + 2048] = r4; q_[tid + 2560] = r5; \
                      q_[tid + 3072] = r6; q_[tid + 3584] = r7; }
// W1 half: [64 k-rows][256 cols]; lane covers cols 4L..4L+3
#define CONSUME(WOFF, KQ) \
    { \
        _Pragma("unroll 2") \
        for (int k4 = 0; k4 < 16; ++k4) { \
            float4 xr[2]; \
            _Pragma("unroll") \
            for (int r = 0; r < 2; ++r) \
                xr[r] = *(const float4*)&LB[XT_O + (row0+r)*128 + (KQ) + k4*4]; \
            _Pragma("unroll") \
            for (int kk = 0; kk < 4; ++kk) { \
                float4 wv = ((const float4*)&LB[(WOFF) + (k4*4+kk)*256])[lane]; \
                v2f wA, wB; wA.x = wv.x; wA.y = wv.y; wB.x = wv.z; wB.y = wv.w; \
                _Pragma("unroll") \
                for (int r = 0; r < 2; ++r) { \
                    float xv = ((const float*)&xr[r])[kk]; \
                    accA[r] += wA * xv; \
                    accB[r] += wB * xv; \
                } \
            } \
        } \
    }

    LOADQ(fc1w);                               // W1 h0(L0) in flight

    // ---------------- proj1: G = gelu(hist @ pw1 + pb1), wave-local rows ----
    {
        const float* hb = hist + ((size_t)b * TT + T0 + q*16) * 4;
        float w0 = pw1[lane], w1 = pw1[64+lane], w2 = pw1[128+lane], w3 = pw1[192+lane];
        float bb = pb1[lane];
        #pragma unroll
        for (int r = 0; r < 2; ++r) {
            int t = row0 + r;
            float4 h = *(const float4*)(hb + t*4);          // wave-uniform
            LB[WB1_O + t*64 + lane] = gelu_exact(bb + h.x*w0 + h.y*w1 + h.z*w2 + h.w*w3);
        }
    }
    WRITEQ(WB0_O);                             // h0 -> B0 (waits its loads)
    LOADQ(fc1w + 16384);                       // h1(L0) in flight
    // ---------------- proj2: X0 = G @ pw2 + pb2 -> XT (wave-local rows) -----
    {
        float2 bv = ((const float2*)pb2)[lane];
        v2f acc[2];
        #pragma unroll
        for (int r = 0; r < 2; ++r) { acc[r].x = 0.f; acc[r].y = 0.f; }
        #pragma unroll 2
        for (int k4 = 0; k4 < 16; ++k4) {
            float4 xr[2];
            #pragma unroll
            for (int r = 0; r < 2; ++r)
                xr[r] = *(const float4*)&LB[WB1_O + (row0+r)*64 + k4*4];  // own rows
            #pragma unroll
            for (int kk = 0; kk < 4; ++kk) {
                v2f w = ((const v2f*)(pw2 + (k4*4+kk)*128))[lane];
                #pragma unroll
                for (int r = 0; r < 2; ++r) {
                    float xv = ((const float*)&xr[r])[kk];
                    acc[r] += w * xv;
                }
            }
        }
        #pragma unroll
        for (int r = 0; r < 2; ++r) {
            float2 o; o.x = acc[r].x + bv.x; o.y = acc[r].y + bv.y;
            *(float2*)&LB[XT_O + (row0+r)*128 + lane*2] = o;
        }
    }

    #pragma unroll 1
    for (int l = 0; l < 4; ++l) {
        const float* W1n = fc1w + (size_t)(l < 3 ? l+1 : l) * 32768;
        const float* W2g = fc2w + (size_t)l * 32768;

        // ---- fc1: H = X @ W1; entry: WB0 = h0(l), regs = h1(l) in flight ---
        v2f accA[2], accB[2];
        #pragma unroll
        for (int r = 0; r < 2; ++r) {
            accA[r].x = 0.f; accA[r].y = 0.f;
            accB[r].x = 0.f; accB[r].y = 0.f;
        }
        __syncthreads(); WRITEQ(WB1_O); LOADQ(W1n);          CONSUME(WB0_O, 0);
        __syncthreads(); WRITEQ(WB0_O); LOADQ(W1n + 16384);  CONSUME(WB1_O, 64);
        // exit: WB0 = h0(l+1) written, regs = h1(l+1) in flight

        // ---- LN1 (same tree/order) ----
        {
            float4 b1v = ((const float4*)(fc1b + l*256))[lane];
            float4 g1v = ((const float4*)(n1g  + l*256))[lane];
            float4 t1v = ((const float4*)(n1b  + l*256))[lane];
            #pragma unroll
            for (int r = 0; r < 2; ++r) {
                float a0 = accA[r].x + b1v.x, a1 = accA[r].y + b1v.y;
                float a2 = accB[r].x + b1v.z, a3 = accB[r].y + b1v.w;
                float s = a0 + a1 + a2 + a3;
                #pragma unroll
                for (int m = 1; m < 64; m <<= 1) s += __shfl_xor(s, m, 64);
                float mean = s * (1.0f/256.0f);
                float dx = a0-mean, dy = a1-mean, dz = a2-mean, dw = a3-mean;
                float q2 = dx*dx + dy*dy + dz*dz + dw*dw;
                #pragma unroll
                for (int m = 1; m < 64; m <<= 1) q2 += __shfl_xor(q2, m, 64);
                float inv = 1.0f / sqrtf(q2 * (1.0f/256.0f) + 1e-5f);
                accA[r].x = dx*inv*g1v.x + t1v.x; accA[r].y = dy*inv*g1v.y + t1v.y;
                accB[r].x = dz*inv*g1v.z + t1v.z; accB[r].y = dw*inv*g1v.w + t1v.w;
            }
        }
        // ---- LIF1: intra-block flag chain; cross-quarter seed/emit ---------
        // Mk[c][i] bit j = spike of col d=4j+c at local step i (reg-resident).
        unsigned long long Mk[4][2];
        {
            const int tgt = l*8 + wave;
            while (__hip_atomic_load(&FLG[0], __ATOMIC_ACQUIRE,
                                     __HIP_MEMORY_SCOPE_WORKGROUP) < tgt)
                __builtin_amdgcn_s_sleep(1);
            float v0, v1, v2, v3;
            if (wave == 0) {
                if (q == 0) { v0 = v1 = v2 = v3 = 0.f; }
                else {
                    while (__hip_atomic_load(&flg1[(q-1)*64 + b], __ATOMIC_RELAXED,
                                             __HIP_MEMORY_SCOPE_AGENT) < l+1)
                        __builtin_amdgcn_s_sleep(1);
                    __builtin_amdgcn_fence(__ATOMIC_ACQUIRE, "agent");
                    float4 vv = *(const float4*)
                        &v1buf[(size_t)(l*3 + (q-1))*NB*256 + b*256 + lane*4];
                    v0 = vv.x; v1 = vv.y; v2 = vv.z; v3 = vv.w;
                }
            } else {
                float4 vv = *(const float4*)&LB[V1_O + lane*4];
                v0 = vv.x; v1 = vv.y; v2 = vv.z; v3 = vv.w;
            }
            #pragma unroll
            for (int i = 0; i < 2; ++i) {
                v0 += (accA[i].x - v0) * 0.5f;
                v1 += (accA[i].y - v1) * 0.5f;
                v2 += (accB[i].x - v2) * 0.5f;
                v3 += (accB[i].y - v3) * 0.5f;
                bool s0 = v0 >= 1.f, s1 = v1 >= 1.f, s2 = v2 >= 1.f, s3 = v3 >= 1.f;
                Mk[0][i] = __ballot(s0); Mk[1][i] = __ballot(s1);
                Mk[2][i] = __ballot(s2); Mk[3][i] = __ballot(s3);
                v0 = s0 ? 0.f : v0;  v1 = s1 ? 0.f : v1;
                v2 = s2 ? 0.f : v2;  v3 = s3 ? 0.f : v3;
            }
            if (wave < 7) {
                float4 vv; vv.x = v0; vv.y = v1; vv.z = v2; vv.w = v3;
                *(float4*)&LB[V1_O + lane*4] = vv;
            } else if (q < 3) {
                float4 vv; vv.x = v0; vv.y = v1; vv.z = v2; vv.w = v3;
                *(float4*)&v1buf[(size_t)(l*3 + q)*NB*256 + b*256 + lane*4] = vv;
                __builtin_amdgcn_fence(__ATOMIC_RELEASE, "agent");
                if (lane == 0)
                    __hip_atomic_store(&flg1[q*64 + b], l+1, __ATOMIC_RELAXED,
                                       __HIP_MEMORY_SCOPE_AGENT);
            }
            if (lane == 0)
                __hip_atomic_store(&FLG[0], tgt+1, __ATOMIC_RELEASE,
                                   __HIP_MEMORY_SCOPE_WORKGROUP);
        }
        // ---- fc2 sparse, ILP-4: 4 ascending indices per iter, 16 loads
        //      issued together, adds in identical ascending order ------------
        float a2x[2], a2y[2];
        #pragma unroll
        for (int i = 0; i < 2; ++i) {
            unsigned long long m0 = Mk[0][i], m1 = Mk[1][i];
            unsigned long long m2 = Mk[2][i], m3 = Mk[3][i];
            unsigned long long mm = m0 | m1 | m2 | m3;
            float ax = 0.f, ay = 0.f;
            int ng = __popcll(mm) >> 2;
            for (int g = 0; g < ng; ++g) {
                int i0 = __builtin_ctzll(mm); mm &= mm - 1;
                int i1 = __builtin_ctzll(mm); mm &= mm - 1;
                int i2 = __builtin_ctzll(mm); mm &= mm - 1;
                int i3 = __builtin_ctzll(mm); mm &= mm - 1;
                const float* p0 = W2g + (size_t)i0 * 512;
                const float* p1 = W2g + (size_t)i1 * 512;
                const float* p2 = W2g + (size_t)i2 * 512;
                const float* p3 = W2g + (size_t)i3 * 512;
                float2 w00 = ((const float2*)(p0      ))[lane];
                float2 w01 = ((const float2*)(p0 + 128))[lane];
                float2 w02 = ((const float2*)(p0 + 256))[lane];
                float2 w03 = ((const float2*)(p0 + 384))[lane];
                float2 w10 = ((const float2*)(p1      ))[lane];
                float2 w11 = ((const float2*)(p1 + 128))[lane];
                float2 w12 = ((const float2*)(p1 + 256))[lane];
                float2 w13 = ((const float2*)(p1 + 384))[lane];
                float2 w20 = ((const float2*)(p2      ))[lane];
                float2 w21 = ((const float2*)(p2 + 128))[lane];
                float2 w22 = ((const float2*)(p2 + 256))[lane];
                float2 w23 = ((const float2*)(p2 + 384))[lane];
                float2 w30 = ((const float2*)(p3      ))[lane];
                float2 w31 = ((const float2*)(p3 + 128))[lane];
                float2 w32 = ((const float2*)(p3 + 256))[lane];
                float2 w33 = ((const float2*)(p3 + 384))[lane];
                unsigned long long b0 = 1ull << i0, b1 = 1ull << i1;
                unsigned long long b2 = 1ull << i2, b3 = 1ull << i3;
                ax += (m0 & b0) ? w00.x : 0.f;  ay += (m0 & b0) ? w00.y : 0.f;
                ax += (m1 & b0) ? w01.x : 0.f;  ay += (m1 & b0) ? w01.y : 0.f;
                ax += (m2 & b0) ? w02.x : 0.f;  ay += (m2 & b0) ? w02.y : 0.f;
                ax += (m3 & b0) ? w03.x : 0.f;  ay += (m3 & b0) ? w03.y : 0.f;
                ax += (m0 & b1) ? w10.x : 0.f;  ay += (m0 & b1) ? w10.y : 0.f;
                ax += (m1 & b1) ? w11.x : 0.f;  ay += (m1 & b1) ? w11.y : 0.f;
                ax += (m2 & b1) ? w12.x : 0.f;  ay += (m2 & b1) ? w12.y : 0.f;
                ax += (m3 & b1) ? w13.x : 0.f;  ay += (m3 & b1) ? w13.y : 0.f;
                ax += (m0 & b2) ? w20.x : 0.f;  ay += (m0 & b2) ? w20.y : 0.f;
                ax += (m1 & b2) ? w21.x : 0.f;  ay += (m1 & b2) ? w21.y : 0.f;
                ax += (m2 & b2) ? w22.x : 0.f;  ay += (m2 & b2) ? w22.y : 0.f;
                ax += (m3 & b2) ? w23.x : 0.f;  ay += (m3 & b2) ? w23.y : 0.f;
                ax += (m0 & b3) ? w30.x : 0.f;  ay += (m0 & b3) ? w30.y : 0.f;
                ax += (m1 & b3) ? w31.x : 0.f;  ay += (m1 & b3) ? w31.y : 0.f;
                ax += (m2 & b3) ? w32.x : 0.f;  ay += (m2 & b3) ? w32.y : 0.f;
                ax += (m3 & b3) ? w33.x : 0.f;  ay += (m3 & b3) ? w33.y : 0.f;
            }
            while (mm) {                       // tail (<=3), same order
                int id = __builtin_ctzll(mm); mm &= mm - 1;
                const float* wr = W2g + (size_t)id * 512;
                float2 w0 = ((const float2*)(wr      ))[lane];
                float2 w1 = ((const float2*)(wr + 128))[lane];
                float2 w2 = ((const float2*)(wr + 256))[lane];
                float2 w3 = ((const float2*)(wr + 384))[lane];
                unsigned long long bit = 1ull << id;
                ax += (m0 & bit) ? w0.x : 0.f;  ay += (m0 & bit) ? w0.y : 0.f;
                ax += (m1 & bit) ? w1.x : 0.f;  ay += (m1 & bit) ? w1.y : 0.f;
                ax += (m2 & bit) ? w2.x : 0.f;  ay += (m2 & bit) ? w2.y : 0.f;
                ax += (m3 & bit) ? w3.x : 0.f;  ay += (m3 & bit) ? w3.y : 0.f;
            }
            a2x[i] = ax; a2y[i] = ay;
        }
        // ---- LN2 (same tree/order) ----
        {
            float2 b2v = ((const float2*)(fc2b + l*128))[lane];
            float2 g2v = ((const float2*)(n2g  + l*128))[lane];
            float2 t2v = ((const float2*)(n2b  + l*128))[lane];
            #pragma unroll
            for (int i = 0; i < 2; ++i) {
                float ax = a2x[i] + b2v.x, ay = a2y[i] + b2v.y;
                float s = ax + ay;
                #pragma unroll
                for (int m = 1; m < 64; m <<= 1) s += __shfl_xor(s, m, 64);
                float mean = s * (1.0f/128.0f);
                float dx = ax - mean, dy = ay - mean;
                float qq = dx*dx + dy*dy;
                #pragma unroll
                for (int m = 1; m < 64; m <<= 1) qq += __shfl_xor(qq, m, 64);
                float inv = 1.0f / sqrtf(qq * (1.0f/128.0f) + 1e-5f);
                a2x[i] = dx*inv*g2v.x + t2v.x;
                a2y[i] = dy*inv*g2v.y + t2v.y;
            }
        }
        // ---- LIF2 + residual on LDS X tile; cross-quarter seed/emit --------
        {
            const int tgt = l*8 + wave;
            while (__hip_atomic_load(&FLG[1], __ATOMIC_ACQUIRE,
                                     __HIP_MEMORY_SCOPE_WORKGROUP) < tgt)
                __builtin_amdgcn_s_sleep(1);
            float u0, u1;
            if (wave == 0) {
                if (q == 0) { u0 = u1 = 0.f; }
                else {
                    while (__hip_atomic_load(&flg2[(q-1)*64 + b], __ATOMIC_RELAXED,
                                             __HIP_MEMORY_SCOPE_AGENT) < l+1)
                        __builtin_amdgcn_s_sleep(1);
                    __builtin_amdgcn_fence(__ATOMIC_ACQUIRE, "agent");
                    float2 uv = *(const float2*)
                        &v2buf[(size_t)(l*3 + (q-1))*NB*128 + b*128 + lane*2];
                    u0 = uv.x; u1 = uv.y;
                }
            } else {
                float2 uv = *(const float2*)&LB[V2_O + lane*2];
                u0 = uv.x; u1 = uv.y;
            }
            #pragma unroll
            for (int i = 0; i < 2; ++i) {
                int t = row0 + i;
                u0 += (a2x[i] - u0) * 0.5f;
                u1 += (a2y[i] - u1) * 0.5f;
                bool s0 = u0 >= 1.f, s1 = u1 >= 1.f;
                float2 xv = *(const float2*)&LB[XT_O + t*128 + lane*2];
                float2 xn;
                xn.x = xv.x + (s0 ? 1.f : 0.f);
                xn.y = xv.y + (s1 ? 1.f : 0.f);
                *(float2*)&LB[XT_O + t*128 + lane*2] = xn;
                u0 = s0 ? 0.f : u0;
                u1 = s1 ? 0.f : u1;
                if (l == 3 && q == 3 && t == 15)
                    ((float2*)(out + b*128))[lane] = xn;     // row t=2047
            }
            if (wave < 7) {
                float2 uv; uv.x = u0; uv.y = u1;
                *(float2*)&LB[V2_O + lane*2] = uv;
            } else if (q < 3) {
                float2 uv; uv.x = u0; uv.y = u1;
                *(float2*)&v2buf[(size_t)(l*3 + q)*NB*128 + b*128 + lane*2] = uv;
                __builtin_amdgcn_fence(__ATOMIC_RELEASE, "agent");
                if (lane == 0)
                    __hip_atomic_store(&flg2[q*64 + b], l+1, __ATOMIC_RELAXED,
                                       __HIP_MEMORY_SCOPE_AGENT);
            }
            if (lane == 0)
                __hip_atomic_store(&FLG[1], tgt+1, __ATOMIC_RELEASE,
                                   __HIP_MEMORY_SCOPE_WORKGROUP);
        }
    }
#undef LOADQ
#undef WRITEQ
#undef CONSUME
}

extern "C" void kernel_launch(void* const* d_in, const int* in_sizes, int n_in,
                              void* d_out, int out_size, void* d_ws, size_t ws_size,
                              hipStream_t stream) {
    const float* hist = (const float*)d_in[0];
    const float* pw1  = (const float*)d_in[1];
    const float* pb1  = (const float*)d_in[2];
    const float* pw2  = (const float*)d_in[3];
    const float* pb2  = (const float*)d_in[4];
    const float* fc1w = (const float*)d_in[5];
    const float* fc1b = (const float*)d_in[6];
    const float* n1g  = (const float*)d_in[7];
    const float* n1b  = (const float*)d_in[8];
    const float* fc2w = (const float*)d_in[9];
    const float* fc2b = (const float*)d_in[10];
    const float* n2g  = (const float*)d_in[11];
    const float* n2b  = (const float*)d_in[12];
    float* out = (float*)d_out;

    char* ws = (char*)d_ws;
    float* v1buf = (float*)ws;                      // [4][3][64][256] = 768 KB
    float* v2buf = (float*)(ws + (1ull << 20));     // [4][3][64][128] = 384 KB
    int*   flg1  = (int*)(ws + (2ull << 20));       // [3*64] (256 padded)
    int*   flg2  = flg1 + 256;

    hipMemsetAsync(flg1, 0, 512 * sizeof(int), stream);
    fused_kernel<<<256, 512, 0, stream>>>(hist, pw1, pb1, pw2, pb2,
                                          fc1w, fc1b, n1g, n1b,
                                          fc2w, fc2b, n2g, n2b,
                                          v1buf, v2buf, flg1, flg2, out);
}